// Round 14
// baseline (420.812 us; speedup 1.0000x reference)
//
#include <hip/hip_runtime.h>

// Greedy NMS: keep[i] = !any(keep[j] for j in knn[i] if j < i)
//
// Round-26: INSTANT per-decision publish via atomic_or (R25 base).
// R25's post-mortem reframed the bottleneck: with per-row decided bits the
// binding constraint is the ROW-LEVEL dependency chain (~390 levels deep:
// L(i) ~ 33 ln M for ~32 uniform preds/row), at ~0.88 us/link. The link is
// dominated by R25's END-OF-PASS ballot republish cadence (~0.3 us) +
// consumer poll offset — not by publish granularity. Fix: a deciding lane
// publishes IMMEDIATELY with global atomic_or of (decided_bit|kept_bit):
//   - commutative -> no ordering hazards: init publish = one OR per word
//     (word starts 0), later per-lane ORs interleave safely; final
//     full-snapshot store is a superset of all ORs -> order-safe.
//   - no ballots / change-gating / republish in the loop at all.
//   - store traffic: ~150K one-time ORs (<=32 RMWs/word), fire-and-forget.
//   - poll side BYTE-IDENTICAL to R25 (validated envelope).
// Predicted link ~0.45 us -> total ~180-240 us kernel.
// Geometry: CHUNK=2048, QRT=2, NCH=74, WCH=8, ICAP=6, ECAP=16.
//
// Output encoding (validated round 4): INT32.
//   d_out[0..M)        : kept flags, 1 / 0
//   d_out[M..M+M*64)   : kept_knn, idx or 150000 (tail doubles as u64 word
//                        scratch, owned by block 73 which never publishes)
// d_ws[0..3]: progress counter (zeroed by init kernel each call)

#define M_ROWS 150000
#define KNN    64
#define BLK    1024
#define QRT    2
#define CHUNK  (BLK * QRT)                        // 2048
#define NCH    ((M_ROWS + CHUNK - 1) / CHUNK)     // 74
#define ICAP   6
#define ECAP   16
#define WCH    8                                  // exl window, chunks (16384 rows)
#define W64PC  (CHUNK / 32)                       // 64 published u64 words/chunk
#define LMW    (((NCH - 1) * CHUNK) / 32)         // 4672 u32 mirror words
#define NBMG   ((NCH - 1) * W64PC)                // 4672 published u64 words
#define OUT_INTS (M_ROWS + M_ROWS * KNN)
#define BMG_INT_OFF (OUT_INTS - NBMG * 2)         // 8B-aligned; rows >= 149854
#define DECFULL 0xffffffffu

__global__ void init_ws_kernel(unsigned int* progress, int* out) {
  const int i = blockIdx.x * blockDim.x + threadIdx.x;
  unsigned long long* bmg64 = (unsigned long long*)(out + BMG_INT_OFF);
  if (i < NBMG) bmg64[i] = 0ull;                  // decided=0, kept=0
  if (i == 0) *progress = 0u;
}

// reload a row and probe preds j in [lo, hi) against the LDS kept-bitmask
__device__ __forceinline__ bool probe_reload(const int* __restrict__ rp,
                                             const unsigned int* lm,
                                             int lo, int hi) {
  bool s = false;
#pragma unroll
  for (int u = 0; u < 16; ++u) {
    int4 d = ((const int4*)rp)[u];
    int js[4] = {d.x, d.y, d.z, d.w};
#pragma unroll
    for (int m = 0; m < 4; ++m) {
      int j = js[m];
      if (j >= lo && j < hi && ((lm[j >> 5] >> (j & 31)) & 1u)) s = true;
    }
  }
  return s;
}

__global__ __launch_bounds__(BLK) void nms_chain_kernel(
    const int* __restrict__ knn,
    int* __restrict__ out,
    unsigned int* __restrict__ progress)
{
  const int b    = blockIdx.x;
  const int t    = threadIdx.x;
  const int base = b * CHUNK;
  const int winb = (b > WCH) ? (base - WCH * CHUNK) : 0;   // exl window base

  unsigned long long* bmg64 = (unsigned long long*)(out + BMG_INT_OFF);

  __shared__ unsigned char      st[CHUNK];        // 0 unk, 1 kept, 2 supp
  __shared__ unsigned short     il[ICAP][CHUNK];  // TRANSPOSED: conflict-free
  __shared__ unsigned short     exl[ECAP][CHUNK]; // TRANSPOSED: conflict-free
  __shared__ unsigned int       lm[LMW];          // mirrored keep bits
  __shared__ unsigned int       sh_p;

  int  rowq[QRT];
  bool vq[QRT], ovf[QRT], eovf[QRT], supp[QRT];
  int  ic[QRT], ec[QRT];

#pragma unroll
  for (int q = 0; q < QRT; ++q) {
    rowq[q] = base + q * BLK + t;
    vq[q]   = rowq[q] < M_ROWS;
    ic[q] = ec[q] = 0;
    ovf[q] = eovf[q] = supp[q] = false;
  }

  // ---- classification: intra-chunk + static-window pred lists ----
#pragma unroll
  for (int q = 0; q < QRT; ++q) {
    if (!vq[q]) continue;
    const int o   = q * BLK + t;
    const int row = rowq[q];
    const int* rp = knn + (long long)row * KNN;
#pragma unroll
    for (int u = 0; u < 16; ++u) {
      int4 d = ((const int4*)rp)[u];
      int js[4] = {d.x, d.y, d.z, d.w};
#pragma unroll
      for (int m = 0; m < 4; ++m) {
        int j = js[m];
        if (j < row) {                            // strict <: ref semantics
          if (j >= base) {
            if (ic[q] < ICAP) il[ic[q]][o] = (unsigned short)(j - base);
            ++ic[q];
          } else if (j >= winb) {
            if (ec[q] < ECAP) exl[ec[q]][o] = (unsigned short)(j - winb);
            ++ec[q];
          }
          // j < winb: covered by the phase-1 reload probe
        }
      }
    }
  }
#pragma unroll
  for (int q = 0; q < QRT; ++q) {
    ovf[q]  = ic[q] > ICAP; if (ovf[q])  ic[q] = ICAP;
    eovf[q] = ec[q] > ECAP; if (eovf[q]) ec[q] = ECAP;
  }

  // ---- pre-wait: read il lists back into registers ----
  unsigned short ilr[QRT][ICAP];
#pragma unroll
  for (int q = 0; q < QRT; ++q)
#pragma unroll
    for (int x = 0; x < ICAP; ++x)
      ilr[q][x] = il[x][q * BLK + t];             // garbage beyond ic[q]: never used

  // ---- phase 1 (off-turn): trigger hint, lm copy, deep-pred probe ----
  int praw1 = 0;
  if (b > WCH) {
    if (t < 64) {
      int pr = 0;
      for (int spin = 0; spin < (1 << 22); ++spin) {
        pr = (int)__hip_atomic_load(progress, __ATOMIC_RELAXED,
                                    __HIP_MEMORY_SCOPE_AGENT);
        if (pr >= b - WCH) break;
        __builtin_amdgcn_s_sleep(2);
      }
      if (t == 0) sh_p = (unsigned int)pr;
    }
    __syncthreads();                              // sh_p visible
    praw1 = (int)sh_p; if (praw1 > b) praw1 = b;
    const int wt = praw1 * W64PC;
    for (int w = t; w < wt; w += BLK) {           // spin: word fully decided
      unsigned long long v = __hip_atomic_load(&bmg64[w], __ATOMIC_RELAXED,
                                               __HIP_MEMORY_SCOPE_AGENT);
      int g1 = 0;
      while (((unsigned int)(v >> 32)) != DECFULL && ++g1 < (1 << 22)) {
        __builtin_amdgcn_s_sleep(1);
        v = __hip_atomic_load(&bmg64[w], __ATOMIC_RELAXED,
                              __HIP_MEMORY_SCOPE_AGENT);
      }
      lm[w] = (unsigned int)v;                    // kept mask (low 32)
    }
    __syncthreads();                              // lm visible
    const int lim = praw1 * CHUNK;
#pragma unroll
    for (int q = 0; q < QRT; ++q)
      if (vq[q])
        supp[q] = probe_reload(knn + (long long)rowq[q] * KNN, lm, 0, lim);
  }
  const int pr1lim = praw1 * CHUNK;

  // ---- build per-thread unresolved ext-pred masks (BEFORE st init) ----
  unsigned int extm[QRT];
  bool eunk[QRT];
#pragma unroll
  for (int q = 0; q < QRT; ++q) {
    extm[q] = 0u; eunk[q] = false;
    if (vq[q] && !supp[q]) {
      const int o = q * BLK + t;
      const int n = ec[q];
#pragma unroll
      for (int x = 0; x < ECAP; ++x) {
        if (x < n) {
          const int j = winb + (int)exl[x][o];
          if (j >= pr1lim) extm[q] |= (1u << x);
        }
      }
      eunk[q] = eovf[q];
    }
  }

  // ---- st init with kept fast path ----
  unsigned char myst[QRT];
#pragma unroll
  for (int q = 0; q < QRT; ++q) {
    myst[q] = (!vq[q] || supp[q]) ? (unsigned char)2
            : ((ic[q] == 0 && !ovf[q] && extm[q] == 0u && !eunk[q])
               ? (unsigned char)1 : (unsigned char)0);
    __hip_atomic_store(&st[q * BLK + t], myst[q],
                       __ATOMIC_RELAXED, __HIP_MEMORY_SCOPE_WORKGROUP);
  }
  __syncthreads();                                // st init visible to all waves

  // ---- initial publish: one OR per word (~96% of rows decided here).
  //      Word starts 0 -> OR == store; commutes with later per-lane ORs.
  const int lane = t & 63;
  const bool pub = (b < NCH - 1);
  if (pub) {
#pragma unroll
    for (int q = 0; q < QRT; ++q) {
      unsigned long long bdec  = __ballot(myst[q] != 0);
      unsigned long long bkept = __ballot(myst[q] == 1);
      const int g = b * W64PC + ((q * BLK + (t & ~63)) >> 5);
      if (lane == 0)
        (void)__hip_atomic_fetch_or(&bmg64[g],
            ((bdec & 0xffffffffull) << 32) | (bkept & 0xffffffffull),
            __ATOMIC_RELAXED, __HIP_MEMORY_SCOPE_AGENT);
      if (lane == 32)
        (void)__hip_atomic_fetch_or(&bmg64[g + 1],
            ((bdec >> 32) << 32) | (bkept >> 32),
            __ATOMIC_RELAXED, __HIP_MEMORY_SCOPE_AGENT);
    }
  }

  bool undec = false;
#pragma unroll
  for (int q = 0; q < QRT; ++q) undec |= (myst[q] == 0);

  // ---- wave-uniform dataflow loop; INSTANT per-decision atomic_or publish
  for (int pass = 0; pass < (1 << 22); ++pass) {
    bool pend = false;
    if (undec) {
#pragma unroll
      for (int q = 0; q < QRT; ++q) {
        if (myst[q] != 0) continue;
        const int o   = q * BLK + t;
        const int row = base + o;
        bool anyK = false, allD = true;
        unsigned int m = extm[q];

        // ext preds: batches of 8; per-row decided bit (hi32), kept (lo32)
        if (m != 0u) {
#pragma unroll
          for (int g = 0; g < 2; ++g) {
            if ((m >> (g * 8)) & 0xffu) {
              unsigned long long vv[8];
#pragma unroll
              for (int x = 0; x < 8; ++x) {
                const int xe = g * 8 + x;
                const int j = winb + (int)exl[xe][o];
                const int w = ((m >> xe) & 1u) ? (j >> 5) : 0;
                vv[x] = __hip_atomic_load(&bmg64[w], __ATOMIC_RELAXED,
                                          __HIP_MEMORY_SCOPE_AGENT);
              }
#pragma unroll
              for (int x = 0; x < 8; ++x) {
                const int xe = g * 8 + x;
                if ((m >> xe) & 1u) {
                  const int j = winb + (int)exl[xe][o];
                  const int bit = j & 31;
                  if ((((unsigned int)(vv[x] >> 32)) >> bit) & 1u) {
                    if ((((unsigned int)vv[x]) >> bit) & 1u) anyK = true;
                    m &= ~(1u << xe);
                  } else pend = true;
                }
              }
            }
          }
          extm[q] = m;
        }

        // intra preds: batched LDS loads
        if (!ovf[q]) {
          unsigned char vsts[ICAP];
#pragma unroll
          for (int x = 0; x < ICAP; ++x) {
            const int ii = (x < ic[q]) ? (int)ilr[q][x] : 0;
            vsts[x] = __hip_atomic_load(&st[ii],
                __ATOMIC_RELAXED, __HIP_MEMORY_SCOPE_WORKGROUP);
          }
#pragma unroll
          for (int x = 0; x < ICAP; ++x) {
            if (x < ic[q]) { anyK |= (vsts[x] == 1); allD &= (vsts[x] != 0); }
          }
        } else {                                  // ultra-rare: rescan LDS
          const int* rp = knn + (long long)row * KNN;
#pragma unroll
          for (int u = 0; u < 16; ++u) {
            int4 d = ((const int4*)rp)[u];
            int js[4] = {d.x, d.y, d.z, d.w};
            unsigned char sv[4];
#pragma unroll
            for (int m2 = 0; m2 < 4; ++m2) {
              const bool in = (js[m2] >= base && js[m2] < row);
              sv[m2] = __hip_atomic_load(&st[in ? (js[m2] - base) : 0],
                  __ATOMIC_RELAXED, __HIP_MEMORY_SCOPE_WORKGROUP);
            }
#pragma unroll
            for (int m2 = 0; m2 < 4; ++m2) {
              if (js[m2] >= base && js[m2] < row) {
                anyK |= (sv[m2] == 1); allD &= (sv[m2] != 0);
              }
            }
          }
        }
        if (extm[q] != 0u) allD = false;

        // eovf rows (rare): full-window rescan, per-row decided bits
        if (!anyK && eunk[q]) {
          const int lo = (pr1lim > winb) ? pr1lim : winb;
          const int* rp = knn + (long long)row * KNN;
          bool ep = false, ak = false;
#pragma unroll
          for (int g = 0; g < 8; ++g) {
            int js[8];
#pragma unroll
            for (int u = 0; u < 2; ++u) {
              int4 d = ((const int4*)rp)[g * 2 + u];
              js[u * 4 + 0] = d.x; js[u * 4 + 1] = d.y;
              js[u * 4 + 2] = d.z; js[u * 4 + 3] = d.w;
            }
            unsigned long long wv[8];
#pragma unroll
            for (int m2 = 0; m2 < 8; ++m2) {
              const bool in = (js[m2] >= lo && js[m2] < base);
              wv[m2] = __hip_atomic_load(&bmg64[in ? (js[m2] >> 5) : 0],
                  __ATOMIC_RELAXED, __HIP_MEMORY_SCOPE_AGENT);
            }
#pragma unroll
            for (int m2 = 0; m2 < 8; ++m2) {
              if (js[m2] >= lo && js[m2] < base) {
                const int bit = js[m2] & 31;
                if ((((unsigned int)(wv[m2] >> 32)) >> bit) & 1u) {
                  if ((((unsigned int)wv[m2]) >> bit) & 1u) ak = true;
                } else ep = true;
              }
            }
          }
          if (ak) anyK = true;
          else if (!ep) eunk[q] = false;
          if (ep) pend = true;
        }
        if (eunk[q]) allD = false;

        if (anyK)      myst[q] = 2;
        else if (allD) myst[q] = 1;
        if (myst[q] != 0) {
          __hip_atomic_store(&st[o], myst[q],
                             __ATOMIC_RELAXED, __HIP_MEMORY_SCOPE_WORKGROUP);
          if (pub) {                              // INSTANT publish
            const int g = b * W64PC + (o >> 5);
            const int bit = o & 31;
            unsigned long long val = (1ull << (32 + bit))
                | ((myst[q] == 1) ? (1ull << bit) : 0ull);
            (void)__hip_atomic_fetch_or(&bmg64[g], val,
                __ATOMIC_RELAXED, __HIP_MEMORY_SCOPE_AGENT);
          }
        }
      }

      // 2 extra LDS-only intra sweeps: collapse intra chain levels
#pragma unroll
      for (int s = 0; s < 2; ++s) {
#pragma unroll
        for (int q = 0; q < QRT; ++q) {
          if (myst[q] != 0 || ovf[q]) continue;
          const int o = q * BLK + t;
          bool anyK = false, allD = true;
          unsigned char vsts[ICAP];
#pragma unroll
          for (int x = 0; x < ICAP; ++x) {
            const int ii = (x < ic[q]) ? (int)ilr[q][x] : 0;
            vsts[x] = __hip_atomic_load(&st[ii],
                __ATOMIC_RELAXED, __HIP_MEMORY_SCOPE_WORKGROUP);
          }
#pragma unroll
          for (int x = 0; x < ICAP; ++x) {
            if (x < ic[q]) { anyK |= (vsts[x] == 1); allD &= (vsts[x] != 0); }
          }
          if (extm[q] != 0u || eunk[q]) allD = false;
          if (anyK)      myst[q] = 2;
          else if (allD) myst[q] = 1;
          if (myst[q] != 0) {
            __hip_atomic_store(&st[o], myst[q],
                               __ATOMIC_RELAXED, __HIP_MEMORY_SCOPE_WORKGROUP);
            if (pub) {                            // INSTANT publish
              const int g = b * W64PC + (o >> 5);
              const int bit = o & 31;
              unsigned long long val = (1ull << (32 + bit))
                  | ((myst[q] == 1) ? (1ull << bit) : 0ull);
              (void)__hip_atomic_fetch_or(&bmg64[g], val,
                  __ATOMIC_RELAXED, __HIP_MEMORY_SCOPE_AGENT);
            }
          }
        }
      }

      undec = false;
#pragma unroll
      for (int q = 0; q < QRT; ++q) undec |= (myst[q] == 0);
    }

    if (__ballot(undec) == 0ull) break;           // wave-uniform exit
    if (__ballot(pend) != 0ull) __builtin_amdgcn_s_sleep(1);
  }

  // ---- final snapshot publish (superset of all ORs -> order-safe) ----
  if (pub) {
#pragma unroll
    for (int q = 0; q < QRT; ++q) {
      unsigned long long bkept = __ballot(myst[q] == 1);
      const int g = b * W64PC + ((q * BLK + (t & ~63)) >> 5);
      if (lane == 0)
        __hip_atomic_store(&bmg64[g],
            (0xffffffffull << 32) | (bkept & 0xffffffffull),
            __ATOMIC_RELAXED, __HIP_MEMORY_SCOPE_AGENT);
      if (lane == 32)
        __hip_atomic_store(&bmg64[g + 1],
            (0xffffffffull << 32) | (bkept >> 32),
            __ATOMIC_RELAXED, __HIP_MEMORY_SCOPE_AGENT);
    }
  }
  __syncthreads();                                // all waves done + published
  if (t == 0)                                     // hint for phase-1 triggers
    __hip_atomic_store(progress, (unsigned int)(b + 1),
                       __ATOMIC_RELAXED, __HIP_MEMORY_SCOPE_AGENT);

  // ---- outputs (off the chain; block 73's knn overwrites dead scratch) ----
  bool kq[QRT];
#pragma unroll
  for (int q = 0; q < QRT; ++q)
    kq[q] = vq[q] && (myst[q] == 1);

#pragma unroll
  for (int q = 0; q < QRT; ++q)
    if (vq[q]) out[rowq[q]] = kq[q] ? 1 : 0;

#pragma unroll
  for (int q = 0; q < QRT; ++q) {
    if (!vq[q]) continue;
    const int row = rowq[q];
    const int* rp = knn + (long long)row * KNN;
    int* orow = out + M_ROWS + (long long)row * KNN;
    const bool k = kq[q];
#pragma unroll
    for (int u = 0; u < 16; ++u) {
      int4 d = ((const int4*)rp)[u];
      int4 o4;
      o4.x = k ? d.x : M_ROWS;
      o4.y = k ? d.y : M_ROWS;
      o4.z = k ? d.z : M_ROWS;
      o4.w = k ? d.w : M_ROWS;
      ((int4*)orow)[u] = o4;
    }
  }
}

extern "C" void kernel_launch(void* const* d_in, const int* in_sizes, int n_in,
                              void* d_out, int out_size, void* d_ws, size_t ws_size,
                              hipStream_t stream) {
  const int* knn = (const int*)d_in[1];
  int* out = (int*)d_out;
  unsigned int* progress = (unsigned int*)d_ws;

  init_ws_kernel<<<(NBMG + BLK - 1) / BLK, BLK, 0, stream>>>(progress, out);
  nms_chain_kernel<<<NCH, BLK, 0, stream>>>(knn, out, progress);
}

// Round 16
// 364.166 us; speedup vs baseline: 1.1556x; 1.1556x over previous
//
#include <hip/hip_runtime.h>

// Greedy NMS: keep[i] = !any(keep[j] for j in knn[i] if j < i)
//
// Round-28: R27 geometry (WCH=16, ECAP=24) + COMPLETION-GATED OUTPUTS.
// R27's correctness failure was a diagnosed race (absmax = 2^31+149504 =
// straggler per-decision atomic_or's decided-bit-31 word landing in the
// scratch AFTER block 73 overwrote it with kept_knn containing 149504):
// since R26's instant ORs, block 73's loop exit no longer causally
// postdates all other blocks' stores -- rows nobody downstream reads can
// OR-publish arbitrarily late. Fix:
//   - counter = "blocks completed": each b<NCH-1 does
//     fetch_add(done,1,RELEASE) after loop -> barrier -> snapshot ->
//     barrier. Release-RMW sequence => acquire reader of the final value
//     synchronizes with EVERY increment (and each barrier drains that
//     block's stores first).
//   - block NCH-1 spins done >= NCH-1 (ACQUIRE) before writing outputs:
//     no scratch store can follow.
//   - phase-1 trigger reads the counter relaxed (hint only; per-word
//     DECFULL spins remain the correctness backstop; praw1 over/under
//     actual completion is safe by construction).
// Geometry test carried from R27: stride model total ~= NCH/(WCH+1) x
// (P+E'); WCH 8->16 should halve the stride count (342 -> ~170-260 us).
//
// Output encoding (validated round 4): INT32.
//   d_out[0..M)        : kept flags, 1 / 0
//   d_out[M..M+M*64)   : kept_knn, idx or 150000 (tail doubles as u64 word
//                        scratch, owned by block 73 which never publishes)
// d_ws[0..3]: completed-blocks counter (zeroed by init kernel each call)

#define M_ROWS 150000
#define KNN    64
#define BLK    1024
#define QRT    2
#define CHUNK  (BLK * QRT)                        // 2048
#define NCH    ((M_ROWS + CHUNK - 1) / CHUNK)     // 74
#define ICAP   6
#define ECAP   24
#define WCH    16                                 // exl window, chunks (32768 rows)
#define W64PC  (CHUNK / 32)                       // 64 published u64 words/chunk
#define LMW    (((NCH - 1) * CHUNK) / 32)         // 4672 u32 mirror words
#define NBMG   ((NCH - 1) * W64PC)                // 4672 published u64 words
#define OUT_INTS (M_ROWS + M_ROWS * KNN)
#define BMG_INT_OFF (OUT_INTS - NBMG * 2)         // 8B-aligned; rows >= 149854
#define DECFULL 0xffffffffu

__global__ void init_ws_kernel(unsigned int* done, int* out) {
  const int i = blockIdx.x * blockDim.x + threadIdx.x;
  unsigned long long* bmg64 = (unsigned long long*)(out + BMG_INT_OFF);
  if (i < NBMG) bmg64[i] = 0ull;                  // decided=0, kept=0
  if (i == 0) *done = 0u;
}

// reload a row and probe preds j in [lo, hi) against the LDS kept-bitmask
__device__ __forceinline__ bool probe_reload(const int* __restrict__ rp,
                                             const unsigned int* lm,
                                             int lo, int hi) {
  bool s = false;
#pragma unroll
  for (int u = 0; u < 16; ++u) {
    int4 d = ((const int4*)rp)[u];
    int js[4] = {d.x, d.y, d.z, d.w};
#pragma unroll
    for (int m = 0; m < 4; ++m) {
      int j = js[m];
      if (j >= lo && j < hi && ((lm[j >> 5] >> (j & 31)) & 1u)) s = true;
    }
  }
  return s;
}

__global__ __launch_bounds__(BLK) void nms_chain_kernel(
    const int* __restrict__ knn,
    int* __restrict__ out,
    unsigned int* __restrict__ done)
{
  const int b    = blockIdx.x;
  const int t    = threadIdx.x;
  const int base = b * CHUNK;
  const int winb = (b > WCH) ? (base - WCH * CHUNK) : 0;   // exl window base

  unsigned long long* bmg64 = (unsigned long long*)(out + BMG_INT_OFF);

  __shared__ unsigned char      st[CHUNK];        // 0 unk, 1 kept, 2 supp
  __shared__ unsigned short     il[ICAP][CHUNK];  // TRANSPOSED: conflict-free
  __shared__ unsigned short     exl[ECAP][CHUNK]; // TRANSPOSED: conflict-free
  __shared__ unsigned int       lm[LMW];          // mirrored keep bits
  __shared__ unsigned int       sh_p;

  int  rowq[QRT];
  bool vq[QRT], ovf[QRT], eovf[QRT], supp[QRT];
  int  ic[QRT], ec[QRT];

#pragma unroll
  for (int q = 0; q < QRT; ++q) {
    rowq[q] = base + q * BLK + t;
    vq[q]   = rowq[q] < M_ROWS;
    ic[q] = ec[q] = 0;
    ovf[q] = eovf[q] = supp[q] = false;
  }

  // ---- classification: intra-chunk + static-window pred lists ----
#pragma unroll
  for (int q = 0; q < QRT; ++q) {
    if (!vq[q]) continue;
    const int o   = q * BLK + t;
    const int row = rowq[q];
    const int* rp = knn + (long long)row * KNN;
#pragma unroll
    for (int u = 0; u < 16; ++u) {
      int4 d = ((const int4*)rp)[u];
      int js[4] = {d.x, d.y, d.z, d.w};
#pragma unroll
      for (int m = 0; m < 4; ++m) {
        int j = js[m];
        if (j < row) {                            // strict <: ref semantics
          if (j >= base) {
            if (ic[q] < ICAP) il[ic[q]][o] = (unsigned short)(j - base);
            ++ic[q];
          } else if (j >= winb) {
            if (ec[q] < ECAP) exl[ec[q]][o] = (unsigned short)(j - winb);
            ++ec[q];
          }
          // j < winb: covered by the phase-1 reload probe
        }
      }
    }
  }
#pragma unroll
  for (int q = 0; q < QRT; ++q) {
    ovf[q]  = ic[q] > ICAP; if (ovf[q])  ic[q] = ICAP;
    eovf[q] = ec[q] > ECAP; if (eovf[q]) ec[q] = ECAP;
  }

  // ---- pre-wait: read il lists back into registers ----
  unsigned short ilr[QRT][ICAP];
#pragma unroll
  for (int q = 0; q < QRT; ++q)
#pragma unroll
    for (int x = 0; x < ICAP; ++x)
      ilr[q][x] = il[x][q * BLK + t];             // garbage beyond ic[q]: never used

  // ---- phase 1 (off-turn): trigger hint, lm copy, deep-pred probe ----
  int praw1 = 0;
  if (b > WCH) {
    if (t < 64) {
      int pr = 0;
      for (int spin = 0; spin < (1 << 22); ++spin) {
        pr = (int)__hip_atomic_load(done, __ATOMIC_RELAXED,
                                    __HIP_MEMORY_SCOPE_AGENT);
        if (pr >= b - WCH) break;
        __builtin_amdgcn_s_sleep(2);
      }
      if (t == 0) sh_p = (unsigned int)pr;
    }
    __syncthreads();                              // sh_p visible
    praw1 = (int)sh_p; if (praw1 > b) praw1 = b;
    const int wt = praw1 * W64PC;
    for (int w = t; w < wt; w += BLK) {           // spin: word fully decided
      unsigned long long v = __hip_atomic_load(&bmg64[w], __ATOMIC_RELAXED,
                                               __HIP_MEMORY_SCOPE_AGENT);
      int g1 = 0;
      while (((unsigned int)(v >> 32)) != DECFULL && ++g1 < (1 << 22)) {
        __builtin_amdgcn_s_sleep(1);
        v = __hip_atomic_load(&bmg64[w], __ATOMIC_RELAXED,
                              __HIP_MEMORY_SCOPE_AGENT);
      }
      lm[w] = (unsigned int)v;                    // kept mask (low 32)
    }
    __syncthreads();                              // lm visible
    const int lim = praw1 * CHUNK;
#pragma unroll
    for (int q = 0; q < QRT; ++q)
      if (vq[q])
        supp[q] = probe_reload(knn + (long long)rowq[q] * KNN, lm, 0, lim);
  }
  const int pr1lim = praw1 * CHUNK;

  // ---- build per-thread unresolved ext-pred masks (BEFORE st init) ----
  unsigned int extm[QRT];
  bool eunk[QRT];
#pragma unroll
  for (int q = 0; q < QRT; ++q) {
    extm[q] = 0u; eunk[q] = false;
    if (vq[q] && !supp[q]) {
      const int o = q * BLK + t;
      const int n = ec[q];
#pragma unroll
      for (int x = 0; x < ECAP; ++x) {
        if (x < n) {
          const int j = winb + (int)exl[x][o];
          if (j >= pr1lim) extm[q] |= (1u << x);
        }
      }
      eunk[q] = eovf[q];
    }
  }

  // ---- st init with kept fast path ----
  unsigned char myst[QRT];
#pragma unroll
  for (int q = 0; q < QRT; ++q) {
    myst[q] = (!vq[q] || supp[q]) ? (unsigned char)2
            : ((ic[q] == 0 && !ovf[q] && extm[q] == 0u && !eunk[q])
               ? (unsigned char)1 : (unsigned char)0);
    __hip_atomic_store(&st[q * BLK + t], myst[q],
                       __ATOMIC_RELAXED, __HIP_MEMORY_SCOPE_WORKGROUP);
  }
  __syncthreads();                                // st init visible to all waves

  // ---- initial publish: one OR per word (most rows decided here) ----
  const int lane = t & 63;
  const bool pub = (b < NCH - 1);
  if (pub) {
#pragma unroll
    for (int q = 0; q < QRT; ++q) {
      unsigned long long bdec  = __ballot(myst[q] != 0);
      unsigned long long bkept = __ballot(myst[q] == 1);
      const int g = b * W64PC + ((q * BLK + (t & ~63)) >> 5);
      if (lane == 0)
        (void)__hip_atomic_fetch_or(&bmg64[g],
            ((bdec & 0xffffffffull) << 32) | (bkept & 0xffffffffull),
            __ATOMIC_RELAXED, __HIP_MEMORY_SCOPE_AGENT);
      if (lane == 32)
        (void)__hip_atomic_fetch_or(&bmg64[g + 1],
            ((bdec >> 32) << 32) | (bkept >> 32),
            __ATOMIC_RELAXED, __HIP_MEMORY_SCOPE_AGENT);
    }
  }

  bool undec = false;
#pragma unroll
  for (int q = 0; q < QRT; ++q) undec |= (myst[q] == 0);

  // ---- wave-uniform dataflow loop; INSTANT per-decision atomic_or publish
  for (int pass = 0; pass < (1 << 22); ++pass) {
    bool pend = false;
    if (undec) {
#pragma unroll
      for (int q = 0; q < QRT; ++q) {
        if (myst[q] != 0) continue;
        const int o   = q * BLK + t;
        const int row = base + o;
        bool anyK = false, allD = true;
        unsigned int m = extm[q];

        // ext preds: 3 batches of 8; per-row decided bit (hi32), kept (lo32)
        if (m != 0u) {
#pragma unroll
          for (int g = 0; g < 3; ++g) {
            if ((m >> (g * 8)) & 0xffu) {
              unsigned long long vv[8];
#pragma unroll
              for (int x = 0; x < 8; ++x) {
                const int xe = g * 8 + x;
                const int j = winb + (int)exl[xe][o];
                const int w = ((m >> xe) & 1u) ? (j >> 5) : 0;
                vv[x] = __hip_atomic_load(&bmg64[w], __ATOMIC_RELAXED,
                                          __HIP_MEMORY_SCOPE_AGENT);
              }
#pragma unroll
              for (int x = 0; x < 8; ++x) {
                const int xe = g * 8 + x;
                if ((m >> xe) & 1u) {
                  const int j = winb + (int)exl[xe][o];
                  const int bit = j & 31;
                  if ((((unsigned int)(vv[x] >> 32)) >> bit) & 1u) {
                    if ((((unsigned int)vv[x]) >> bit) & 1u) anyK = true;
                    m &= ~(1u << xe);
                  } else pend = true;
                }
              }
            }
          }
          extm[q] = m;
        }

        // intra preds: batched LDS loads
        if (!ovf[q]) {
          unsigned char vsts[ICAP];
#pragma unroll
          for (int x = 0; x < ICAP; ++x) {
            const int ii = (x < ic[q]) ? (int)ilr[q][x] : 0;
            vsts[x] = __hip_atomic_load(&st[ii],
                __ATOMIC_RELAXED, __HIP_MEMORY_SCOPE_WORKGROUP);
          }
#pragma unroll
          for (int x = 0; x < ICAP; ++x) {
            if (x < ic[q]) { anyK |= (vsts[x] == 1); allD &= (vsts[x] != 0); }
          }
        } else {                                  // ultra-rare: rescan LDS
          const int* rp = knn + (long long)row * KNN;
#pragma unroll
          for (int u = 0; u < 16; ++u) {
            int4 d = ((const int4*)rp)[u];
            int js[4] = {d.x, d.y, d.z, d.w};
            unsigned char sv[4];
#pragma unroll
            for (int m2 = 0; m2 < 4; ++m2) {
              const bool in = (js[m2] >= base && js[m2] < row);
              sv[m2] = __hip_atomic_load(&st[in ? (js[m2] - base) : 0],
                  __ATOMIC_RELAXED, __HIP_MEMORY_SCOPE_WORKGROUP);
            }
#pragma unroll
            for (int m2 = 0; m2 < 4; ++m2) {
              if (js[m2] >= base && js[m2] < row) {
                anyK |= (sv[m2] == 1); allD &= (sv[m2] != 0);
              }
            }
          }
        }
        if (extm[q] != 0u) allD = false;

        // eovf rows (rare): full-window rescan, per-row decided bits
        if (!anyK && eunk[q]) {
          const int lo = (pr1lim > winb) ? pr1lim : winb;
          const int* rp = knn + (long long)row * KNN;
          bool ep = false, ak = false;
#pragma unroll
          for (int g = 0; g < 8; ++g) {
            int js[8];
#pragma unroll
            for (int u = 0; u < 2; ++u) {
              int4 d = ((const int4*)rp)[g * 2 + u];
              js[u * 4 + 0] = d.x; js[u * 4 + 1] = d.y;
              js[u * 4 + 2] = d.z; js[u * 4 + 3] = d.w;
            }
            unsigned long long wv[8];
#pragma unroll
            for (int m2 = 0; m2 < 8; ++m2) {
              const bool in = (js[m2] >= lo && js[m2] < base);
              wv[m2] = __hip_atomic_load(&bmg64[in ? (js[m2] >> 5) : 0],
                  __ATOMIC_RELAXED, __HIP_MEMORY_SCOPE_AGENT);
            }
#pragma unroll
            for (int m2 = 0; m2 < 8; ++m2) {
              if (js[m2] >= lo && js[m2] < base) {
                const int bit = js[m2] & 31;
                if ((((unsigned int)(wv[m2] >> 32)) >> bit) & 1u) {
                  if ((((unsigned int)wv[m2]) >> bit) & 1u) ak = true;
                } else ep = true;
              }
            }
          }
          if (ak) anyK = true;
          else if (!ep) eunk[q] = false;
          if (ep) pend = true;
        }
        if (eunk[q]) allD = false;

        if (anyK)      myst[q] = 2;
        else if (allD) myst[q] = 1;
        if (myst[q] != 0) {
          __hip_atomic_store(&st[o], myst[q],
                             __ATOMIC_RELAXED, __HIP_MEMORY_SCOPE_WORKGROUP);
          if (pub) {                              // INSTANT publish
            const int g = b * W64PC + (o >> 5);
            const int bit = o & 31;
            unsigned long long val = (1ull << (32 + bit))
                | ((myst[q] == 1) ? (1ull << bit) : 0ull);
            (void)__hip_atomic_fetch_or(&bmg64[g], val,
                __ATOMIC_RELAXED, __HIP_MEMORY_SCOPE_AGENT);
          }
        }
      }

      // 2 extra LDS-only intra sweeps: collapse intra chain levels
#pragma unroll
      for (int s = 0; s < 2; ++s) {
#pragma unroll
        for (int q = 0; q < QRT; ++q) {
          if (myst[q] != 0 || ovf[q]) continue;
          const int o = q * BLK + t;
          bool anyK = false, allD = true;
          unsigned char vsts[ICAP];
#pragma unroll
          for (int x = 0; x < ICAP; ++x) {
            const int ii = (x < ic[q]) ? (int)ilr[q][x] : 0;
            vsts[x] = __hip_atomic_load(&st[ii],
                __ATOMIC_RELAXED, __HIP_MEMORY_SCOPE_WORKGROUP);
          }
#pragma unroll
          for (int x = 0; x < ICAP; ++x) {
            if (x < ic[q]) { anyK |= (vsts[x] == 1); allD &= (vsts[x] != 0); }
          }
          if (extm[q] != 0u || eunk[q]) allD = false;
          if (anyK)      myst[q] = 2;
          else if (allD) myst[q] = 1;
          if (myst[q] != 0) {
            __hip_atomic_store(&st[o], myst[q],
                               __ATOMIC_RELAXED, __HIP_MEMORY_SCOPE_WORKGROUP);
            if (pub) {                            // INSTANT publish
              const int g = b * W64PC + (o >> 5);
              const int bit = o & 31;
              unsigned long long val = (1ull << (32 + bit))
                  | ((myst[q] == 1) ? (1ull << bit) : 0ull);
              (void)__hip_atomic_fetch_or(&bmg64[g], val,
                  __ATOMIC_RELAXED, __HIP_MEMORY_SCOPE_AGENT);
            }
          }
        }
      }

      undec = false;
#pragma unroll
      for (int q = 0; q < QRT; ++q) undec |= (myst[q] == 0);
    }

    if (__ballot(undec) == 0ull) break;           // wave-uniform exit
    if (__ballot(pend) != 0ull) __builtin_amdgcn_s_sleep(1);
  }

  // ---- final snapshot publish (superset of all ORs -> order-safe) ----
  __syncthreads();                                // all waves' loop done
  if (pub) {
#pragma unroll
    for (int q = 0; q < QRT; ++q) {
      unsigned long long bkept = __ballot(myst[q] == 1);
      const int g = b * W64PC + ((q * BLK + (t & ~63)) >> 5);
      if (lane == 0)
        __hip_atomic_store(&bmg64[g],
            (0xffffffffull << 32) | (bkept & 0xffffffffull),
            __ATOMIC_RELAXED, __HIP_MEMORY_SCOPE_AGENT);
      if (lane == 32)
        __hip_atomic_store(&bmg64[g + 1],
            (0xffffffffull << 32) | (bkept >> 32),
            __ATOMIC_RELAXED, __HIP_MEMORY_SCOPE_AGENT);
    }
  }
  __syncthreads();                                // snapshot stores drained
  if (pub && t == 0)                              // completion count (RELEASE)
    (void)__hip_atomic_fetch_add(done, 1u,
        __ATOMIC_RELEASE, __HIP_MEMORY_SCOPE_AGENT);

  // ---- block NCH-1: GATE outputs on global completion (ACQUIRE) ----
  // All other blocks' ORs + snapshots happen-before done==NCH-1 via the
  // release-RMW sequence; after this no store targets the scratch.
  if (b == NCH - 1) {
    if (t < 64) {
      for (int spin = 0; spin < (1 << 22); ++spin) {
        unsigned int dv = __hip_atomic_load(done, __ATOMIC_ACQUIRE,
                                            __HIP_MEMORY_SCOPE_AGENT);
        if (dv >= (unsigned int)(NCH - 1)) break;
        __builtin_amdgcn_s_sleep(2);
      }
    }
    __syncthreads();                              // gate passed block-wide
  }

  // ---- outputs (block 73's knn overwrites now-dead scratch) ----
  bool kq[QRT];
#pragma unroll
  for (int q = 0; q < QRT; ++q)
    kq[q] = vq[q] && (myst[q] == 1);

#pragma unroll
  for (int q = 0; q < QRT; ++q)
    if (vq[q]) out[rowq[q]] = kq[q] ? 1 : 0;

#pragma unroll
  for (int q = 0; q < QRT; ++q) {
    if (!vq[q]) continue;
    const int row = rowq[q];
    const int* rp = knn + (long long)row * KNN;
    int* orow = out + M_ROWS + (long long)row * KNN;
    const bool k = kq[q];
#pragma unroll
    for (int u = 0; u < 16; ++u) {
      int4 d = ((const int4*)rp)[u];
      int4 o4;
      o4.x = k ? d.x : M_ROWS;
      o4.y = k ? d.y : M_ROWS;
      o4.z = k ? d.z : M_ROWS;
      o4.w = k ? d.w : M_ROWS;
      ((int4*)orow)[u] = o4;
    }
  }
}

extern "C" void kernel_launch(void* const* d_in, const int* in_sizes, int n_in,
                              void* d_out, int out_size, void* d_ws, size_t ws_size,
                              hipStream_t stream) {
  const int* knn = (const int*)d_in[1];
  int* out = (int*)d_out;
  unsigned int* done = (unsigned int*)d_ws;

  init_ws_kernel<<<(NBMG + BLK - 1) / BLK, BLK, 0, stream>>>(done, out);
  nms_chain_kernel<<<NCH, BLK, 0, stream>>>(knn, out, done);
}